// Round 1
// baseline (251.158 us; speedup 1.0000x reference)
//
#include <hip/hip_runtime.h>

// FirstFrameBiasedEMA: y[0]=x[0]; y[t]=a*y[t-1]+(1-a)*x[t], a=0.9
// x: [B=16, T=4096, C=512] fp32.
//
// R3: memory-level-parallelism fix. R2 was latency-bound (~880 cy per 1KB
// wave-load = 1 outstanding load/SIMD; 2.8 TB/s vs 6.3 achievable). The
// unroll-8 loop compiled to load->wait->fma->store per element. This version
// hand-pipelines: 2 register buffers x 8 float4, fully unrolled so all
// indices are compile-time (no scratch), with batch k+2's loads issued right
// after batch k is consumed -> ~16 loads in flight per wave, 32 per SIMD.
// Little's law needs only ~2.3 KB/SIMD in flight for 6.3 TB/s; this gives 32KB.
//
// Geometry unchanged from R2 (known-good absmax 0.0078): chunk L=64, lookback
// W=64 (alpha^64 ~ 1.2e-3), 1024 rows x 128 lanes, 2 rows per 256-thread block.

constexpr int T = 4096;
constexpr int C = 512;
constexpr int C4 = C / 4;     // float4 per row = 128
constexpr int L = 64;         // chunk length along T
constexpr int W = 64;         // lookback warm-up length
constexpr int CHUNKS = T / L; // 64
constexpr int PF = 8;         // float4 loads per batch

__device__ __forceinline__ void ema1(float4& yv, const float4& xv) {
    yv.x = 0.9f * yv.x + 0.1f * xv.x;
    yv.y = 0.9f * yv.y + 0.1f * xv.y;
    yv.z = 0.9f * yv.z + 0.1f * xv.z;
    yv.w = 0.9f * yv.w + 0.1f * xv.w;
}

__device__ __forceinline__ void load8(const float4* __restrict__ p, float4 (&b)[PF]) {
    #pragma unroll
    for (int i = 0; i < PF; ++i) b[i] = p[(size_t)i * C4];
}

__global__ __launch_bounds__(256) void ema_chunk_kernel(
    const float4* __restrict__ x, float4* __restrict__ y)
{
    const int lane     = threadIdx.x & (C4 - 1);    // 0..127, float4 index in C
    const int rowInBlk = threadIdx.x >> 7;          // 0..1
    const int row      = blockIdx.x * 2 + rowInBlk; // 0..B*CHUNKS-1
    const int chunk    = row & (CHUNKS - 1);
    const int b        = row >> 6;                  // row / CHUNKS
    const int t0       = chunk * L;

    const size_t base = (size_t)b * T * C4 + lane;

    float4 buf[2][PF];   // fully-unrolled loops only: indices stay compile-time
    float4 yv;

    if (chunk == 0) {
        // 8 batches, all stored. Batch 0 elem 0 is the passthrough frame.
        const float4* xp = x + base;
        float4*       yp = y + base;
        load8(xp, buf[0]);
        load8(xp + PF * C4, buf[1]);
        const float4* xn = xp + 2 * PF * C4;
        #pragma unroll
        for (int k = 0; k < L / PF; ++k) {
            float4 (&cb)[PF] = buf[k & 1];
            if (k == 0) {
                yv = cb[0];
                yp[0] = yv;
                #pragma unroll
                for (int i = 1; i < PF; ++i) { ema1(yv, cb[i]); yp[(size_t)i * C4] = yv; }
            } else {
                #pragma unroll
                for (int i = 0; i < PF; ++i) {
                    ema1(yv, cb[i]);
                    yp[(size_t)(k * PF + i) * C4] = yv;
                }
            }
            if (k + 2 < L / PF) { load8(xn, buf[k & 1]); xn += PF * C4; }
        }
    } else {
        // 16 batches: 0..7 warm-up (batch 0 elem 0 seeds), 8..15 stored.
        const float4* xp = x + base + (size_t)(t0 - W) * C4;
        float4*       yp = y + base + (size_t)t0 * C4;
        load8(xp, buf[0]);
        load8(xp + PF * C4, buf[1]);
        const float4* xn = xp + 2 * PF * C4;
        #pragma unroll
        for (int k = 0; k < (W + L) / PF; ++k) {
            float4 (&cb)[PF] = buf[k & 1];
            if (k == 0) {
                yv = cb[0];
                #pragma unroll
                for (int i = 1; i < PF; ++i) ema1(yv, cb[i]);
            } else if (k < W / PF) {
                #pragma unroll
                for (int i = 0; i < PF; ++i) ema1(yv, cb[i]);
            } else {
                #pragma unroll
                for (int i = 0; i < PF; ++i) {
                    ema1(yv, cb[i]);
                    yp[(size_t)((k - W / PF) * PF + i) * C4] = yv;
                }
            }
            if (k + 2 < (W + L) / PF) { load8(xn, buf[k & 1]); xn += PF * C4; }
        }
    }
}

extern "C" void kernel_launch(void* const* d_in, const int* in_sizes, int n_in,
                              void* d_out, int out_size, void* d_ws, size_t ws_size,
                              hipStream_t stream) {
    const float4* x = (const float4*)d_in[0];
    float4* y = (float4*)d_out;
    const int B = in_sizes[0] / (T * C);  // 16

    const int rows = B * CHUNKS;          // 1024
    dim3 grid(rows / 2);                  // 2 rows per 256-thread block
    dim3 block(256);
    ema_chunk_kernel<<<grid, block, 0, stream>>>(x, y);
}